// Round 2
// baseline (301.908 us; speedup 1.0000x reference)
//
#include <hip/hip_runtime.h>

// FilteredNoise: DDSP filtered noise, FFT-free.
// zp[d] = (1/129)(fr0 + 2*sum_{k=1..64} fr_k cos(2*pi*k*d/129)), even-symmetric
// wir[j] = hann_periodic(j,129) * zp[(j-64) mod 129]; j=128 tap dropped (win=5.9e-4)
// out[b,64*fp+r] = sum_{dd=0..2} sum_s n[fp-dd][s] * wir[fp-dd][64*dd+r-s]
//
// Round-2 revision (FMA-density pass):
//  - 16 output samples per thread (was 8): rolling 5-quad window, each s4-iter
//    does 64 FMAs per 2 ds_read_b128 (was 32) -> LDS reads per MAC halved,
//    FMA issue density ~89%; 128 issue-cycles of FMA per iter self-hides LDS latency.
//  - G=32 frames/block, 128 threads = 32 chunks x 4 t-slots; t = tid>>5 so each
//    wave owns t in {2wv, 2wv+1} -> triangle skips stay wave-uniform
//    (wave0 skips dd0 s4>=8, wave1 skips dd2 s4<=7; 40 iters/wave).
//  - odd quad strides kept (wirP 49 quads, nS 17 quads): aligned b128, floor-level
//    bank behavior. LDS 36.4KB -> 4 blocks/CU (occupancy traded for per-wave ILP).

#define NB 64
#define FTOT 4097
#define FCL 65
#define SAMPLES 262144
#define OUT_FRAMES 4096
#define G 32                     // output frames per block
#define NF (G + 2)               // staged frames (2 overlap)
#define NSTRIDE 68               // nS row stride: 17 quads (odd)
#define PW 196                   // wirP row stride: 49 quads (odd); data floats [33..159]
#define BLOCKS_PER_B (OUT_FRAMES / G)   // 128

__device__ __forceinline__ float mod_sigmoid(float x) {
    float s = 1.0f / (1.0f + __expf(-x));
    return 2.0f * __expf(2.302585092994046f * __logf(s)) + 1e-7f;   // 2*s^ln(10)+1e-7
}

__device__ __forceinline__ float rdlane(float v, int k) {
    return __int_as_float(__builtin_amdgcn_readlane(__float_as_int(v), k));
}

// One dd-pass: 16 outputs (r = 16t..16t+15), rolling 5-quad w-window.
// wq points at quad (row_base + 8 + 16*dd + 4*t); A(s4) = that - s4.
// Window for iter s4: quads A-1..A+3 = taps [tap0-4, tap0+15], tap0 = 64dd+16t-4s4.
// a[j] += n[4*s4+i] * w[4 + j - i]  (w[4+d] holds tap tap0+d).
template<int S0, int S1>
__device__ __forceinline__ void conv_dd(const float4* __restrict__ wq,
                                        const float4* __restrict__ nq,
                                        float a[16]) {
    float4 W1 = wq[-S0];
    float4 W2 = wq[-S0 + 1];
    float4 W3 = wq[-S0 + 2];
    float4 W4 = wq[-S0 + 3];
    #pragma unroll
    for (int s4 = S0; s4 < S1; ++s4) {
        float4 W0 = wq[-s4 - 1];                 // fresh aligned ds_read_b128
        float4 n4 = nq[s4];
        float w[20] = {W0.x, W0.y, W0.z, W0.w,
                       W1.x, W1.y, W1.z, W1.w,
                       W2.x, W2.y, W2.z, W2.w,
                       W3.x, W3.y, W3.z, W3.w,
                       W4.x, W4.y, W4.z, W4.w};
        float nv[4] = {n4.x, n4.y, n4.z, n4.w};
        #pragma unroll
        for (int i = 0; i < 4; ++i)
            #pragma unroll
            for (int j = 0; j < 16; ++j)
                a[j] = __builtin_fmaf(nv[i], w[4 + j - i], a[j]);
        W4 = W3; W3 = W2; W2 = W1; W1 = W0;      // roll window (renamed, free)
    }
}

__global__ __launch_bounds__(128, 2) void fn_kernel(
    const float* __restrict__ coeff,   // (64, 4097, 65)
    const float* __restrict__ noise,   // (64, 4097, 64)
    float* __restrict__ out)           // (64, 262144)
{
    __shared__ __align__(16) float costab[132];          // cos(2*pi*m/129), m<=128
    __shared__ __align__(16) float nS[NF * NSTRIDE];     // noise*2-1 (zero f<0)
    __shared__ __align__(16) float wirP[NF * PW];        // tap k at float k+32

    const int tid  = threadIdx.x;
    const int lane = tid & 63;
    const int wv   = tid >> 6;                           // wave id 0..1
    const int blk  = blockIdx.x;
    const int b    = blk / BLOCKS_PER_B;
    const int cg   = blk % BLOCKS_PER_B;
    const int fp0  = cg * G;
    const int fbase = fp0 - 2;

    // zero only the pad quads of wirP: quads 0..8 (taps<0 + tap0 slot) and 40..48
    // (scatter fills floats 33..159; float 32 = tap 0 has hann(0)=0 -> stays zero)
    for (int i = tid; i < NF * 18; i += 128) {
        int row = i / 18, z = i - row * 18;
        int qz = (z < 9) ? z : (z + 31);                 // 0..8, 40..48
        ((float4*)wirP)[row * 49 + qz] = make_float4(0.f, 0.f, 0.f, 0.f);
    }
    for (int i = tid; i < 129; i += 128)
        costab[i] = __cosf(6.283185307179586f * (float)i * (1.0f / 129.0f));

    // stage noise (float4), zero where frame < 0
    for (int i = tid; i < NF * 16; i += 128) {
        int q = i >> 4, g = i & 15;
        int f = fbase + q;
        float4 v = make_float4(0.f, 0.f, 0.f, 0.f);
        if (f >= 0) {
            const float4* src = (const float4*)(noise + ((size_t)b * FTOT + f) * 64);
            float4 u = src[g];
            v = make_float4(2.f*u.x-1.f, 2.f*u.y-1.f, 2.f*u.z-1.f, 2.f*u.w-1.f);
        }
        *(float4*)&nS[q * NSTRIDE + 4 * g] = v;
    }

    // preload this wave's 17 frame spectra (frames wv, wv+2, ..., wv+32)
    float frv[17], f64v[17];
    #pragma unroll
    for (int i = 0; i < 17; ++i) {
        int f = fbase + wv + 2 * i;
        if (f < 0) f = 0;                        // garbage wir nulled via n=0
        const float* row = coeff + ((size_t)b * FTOT + f) * FCL;
        frv[i]  = row[lane];
        f64v[i] = row[64];
    }
    #pragma unroll
    for (int i = 0; i < 17; ++i) {
        frv[i]  = mod_sigmoid(frv[i]);
        f64v[i] = mod_sigmoid(f64v[i]);
    }

    __syncthreads();   // wirP zeros + nS + costab visible

    // transform: shared Chebyshev recurrence across the wave's 17 frames
    {
        float c  = costab[lane];
        float c2 = 2.0f * c;
        float cp = 1.0f;         // cos(0)
        float ck = c;            // cos(theta)
        float S[17];
        #pragma unroll
        for (int i = 0; i < 17; ++i) S[i] = 0.5f * rdlane(frv[i], 0);   // 0.5*fr0
        #pragma unroll 8
        for (int k = 1; k < 64; ++k) {
            #pragma unroll
            for (int i = 0; i < 17; ++i)
                S[i] = __builtin_fmaf(rdlane(frv[i], k), ck, S[i]);
            float cn = __builtin_fmaf(c2, ck, -cp);
            cp = ck; ck = cn;
        }
        // k = 64 term: ck = cos(64*theta)
        #pragma unroll
        for (int i = 0; i < 17; ++i)
            S[i] = __builtin_fmaf(f64v[i], ck, S[i]);
        // window + scatter: zp = 2*S/129; taps k = 64 +- lane at float (k+32) = 96 +- lane
        float w1f = 0.5f - 0.5f * costab[64 + lane];
        float w2f = 0.5f - 0.5f * costab[64 - lane];
        #pragma unroll
        for (int i = 0; i < 17; ++i) {
            int fi = wv + 2 * i;
            float zp = S[i] * (2.0f / 129.0f);
            wirP[fi * PW + 96 + lane] = w1f * zp;
            wirP[fi * PW + 96 - lane] = w2f * zp;
        }
    }
    __syncthreads();

    // conv + OLA: thread = (chunk = output frame, t = sample 16-tet), 16 samples each
    {
        const int chunk = tid & 31;              // output frame within block
        const int t     = tid >> 5;              // r0 = 16*t; wave wv has t in {2wv,2wv+1}
        float a[16];
        #pragma unroll
        for (int j = 0; j < 16; ++j) a[j] = 0.0f;

        // dd = 0: frame fp (q = chunk+2). wave0 (r0<=16): taps 16-4*s4+15 < 0 for s4>=8.
        {
            const int q = chunk + 2;
            const float4* wq = (const float4*)&wirP[q * PW] + (8 + 4 * t);
            const float4* nq = (const float4*)&nS[q * NSTRIDE];
            if (wv == 0) conv_dd<0, 8>(wq, nq, a);
            else         conv_dd<0, 16>(wq, nq, a);
        }
        // dd = 1: frame fp-1 (q = chunk+1), dense
        {
            const int q = chunk + 1;
            const float4* wq = (const float4*)&wirP[q * PW] + (24 + 4 * t);
            const float4* nq = (const float4*)&nS[q * NSTRIDE];
            conv_dd<0, 16>(wq, nq, a);
        }
        // dd = 2: frame fp-2 (q = chunk). wave1 (r0>=32): taps 128+32-4*s4-3 > 127 for s4<=7.
        {
            const int q = chunk;
            const float4* wq = (const float4*)&wirP[q * PW] + (40 + 4 * t);
            const float4* nq = (const float4*)&nS[q * NSTRIDE];
            if (wv == 0) conv_dd<0, 16>(wq, nq, a);
            else         conv_dd<8, 16>(wq, nq, a);
        }

        float* op = &out[(size_t)b * SAMPLES + (size_t)(fp0 + chunk) * 64 + t * 16];
        *(float4*)op        = make_float4(a[0],  a[1],  a[2],  a[3]);
        *(float4*)(op + 4)  = make_float4(a[4],  a[5],  a[6],  a[7]);
        *(float4*)(op + 8)  = make_float4(a[8],  a[9],  a[10], a[11]);
        *(float4*)(op + 12) = make_float4(a[12], a[13], a[14], a[15]);
    }
}

extern "C" void kernel_launch(void* const* d_in, const int* in_sizes, int n_in,
                              void* d_out, int out_size, void* d_ws, size_t ws_size,
                              hipStream_t stream) {
    const float* coeff = (const float*)d_in[0];
    const float* noise = (const float*)d_in[1];
    float* out = (float*)d_out;
    dim3 grid(NB * BLOCKS_PER_B);   // 64 * 128 = 8192 blocks, 128 threads each
    fn_kernel<<<grid, 128, 0, stream>>>(coeff, noise, out);
}

// Round 4
// 301.107 us; speedup vs baseline: 1.0027x; 1.0027x over previous
//
#include <hip/hip_runtime.h>

// FilteredNoise: DDSP filtered noise, FFT-free.
// zp[d] = (1/129)(fr0 + 2*sum_{k=1..64} fr_k cos(2*pi*k*d/129)), even-symmetric
// wir[j] = hann_periodic(j,129) * zp[(j-64) mod 129]; j=128 tap dropped (win=5.9e-4)
// out[b,64*fp+r] = sum_{dd=0..2} sum_s n[fp-dd][s] * wir[fp-dd][64*dd+r-s]
//
// Round-4 = Round-3 resubmit (previous bench died to container infra, no data):
//  - LDS = wirP ONLY (26.7KB -> 5-6 blocks/CU of 4-wave blocks; lb(256,5)).
//    noise read directly from global in the conv loop (8.7KB/block working set,
//    L1/L2-resident; per-s4 wave reads are chunk-unique -> coalesce/broadcast).
//    2u-1 folded as 4 fma/quad. costab dropped (3 direct __cosf/thread).
//  - f<0 frames: wir row ZEROED in transform via vm mask (noise no longer zero!).
//  - G=32, 256 threads, 8-samp conv (R1's proven density). 4 waves give finer
//    wave-uniform triangle bounds: dd0 S1=4(wv+1), dd2 S0=4wv -> 36 iters/wave,
//    exactly balanced. Runtime bounds + unroll 4 keeps code small.

#define NB 64
#define FTOT 4097
#define FCL 65
#define SAMPLES 262144
#define OUT_FRAMES 4096
#define G 32                     // output frames per block
#define NF (G + 2)               // 34 staged frames (2 overlap)
#define PW 196                   // wirP row stride: 49 quads (odd -> bank permutation)
#define BLOCKS_PER_B (OUT_FRAMES / G)   // 128

__device__ __forceinline__ float mod_sigmoid(float x) {
    float s = 1.0f / (1.0f + __expf(-x));
    return 2.0f * __expf(2.302585092994046f * __logf(s)) + 1e-7f;   // 2*s^ln(10)+1e-7
}

__device__ __forceinline__ float rdlane(float v, int k) {
    return __int_as_float(__builtin_amdgcn_readlane(__float_as_int(v), k));
}

// One dd-pass: 8 outputs, rolling 3-quad window, runtime bounds (multiples of 4).
// wb biased so ALL offsets are non-negative: W0(s4) = wb[15-s4] = quad of tap (tap0-4),
// tap0 = 64dd + 8t - 4s4; w[m] = tap (tap0-4+m); a[j] += nv[i]*w[4+j-i].
__device__ __forceinline__ void conv_dd(const float4* __restrict__ wb,
                                        const float4* __restrict__ np4,
                                        int S0, int S1, float a[8]) {
    float4 W1 = wb[16 - S0];
    float4 W2 = wb[17 - S0];
    #pragma unroll 4
    for (int s4 = S0; s4 < S1; ++s4) {
        float4 W0 = wb[15 - s4];                 // aligned ds_read_b128
        float4 u  = np4[s4];                     // global (L1/L2-resident)
        float nv[4] = {__builtin_fmaf(u.x, 2.f, -1.f),
                       __builtin_fmaf(u.y, 2.f, -1.f),
                       __builtin_fmaf(u.z, 2.f, -1.f),
                       __builtin_fmaf(u.w, 2.f, -1.f)};
        float w[12] = {W0.x, W0.y, W0.z, W0.w,
                       W1.x, W1.y, W1.z, W1.w,
                       W2.x, W2.y, W2.z, W2.w};
        #pragma unroll
        for (int i = 0; i < 4; ++i)
            #pragma unroll
            for (int j = 0; j < 8; ++j)
                a[j] = __builtin_fmaf(nv[i], w[4 + j - i], a[j]);
        W2 = W1; W1 = W0;                        // roll window
    }
}

__global__ __launch_bounds__(256, 5) void fn_kernel(
    const float* __restrict__ coeff,   // (64, 4097, 65)
    const float* __restrict__ noise,   // (64, 4097, 64)
    float* __restrict__ out)           // (64, 262144)
{
    __shared__ __align__(16) float wirP[NF * PW];        // tap k at float k+32

    const int tid  = threadIdx.x;
    const int lane = tid & 63;
    const int wv   = tid >> 6;                           // wave id 0..3
    const int blk  = blockIdx.x;
    const int b    = blk / BLOCKS_PER_B;
    const int cg   = blk % BLOCKS_PER_B;
    const int fp0  = cg * G;
    const int fbase = fp0 - 2;

    // zero only pad quads {0..8, 40..48} per row (scatter fills floats 33..159;
    // float 32 = tap 0 has hann(0)=0, floats 160..195 = dropped/pad region)
    for (int i = tid; i < NF * 18; i += 256) {
        int row = i / 18, z = i - row * 18;
        int qz = (z < 9) ? z : (z + 31);                 // 0..8, 40..48
        ((float4*)wirP)[row * 49 + qz] = make_float4(0.f, 0.f, 0.f, 0.f);
    }

    // preload this wave's 9 frame spectra (frames fi = wv + 4*i)
    float frv[9], f64v[9], vm[9];
    #pragma unroll
    for (int i = 0; i < 9; ++i) {
        int fi = wv + 4 * i;
        int f  = fbase + fi;
        vm[i] = (f >= 0 && fi < NF) ? 1.f : 0.f;         // invalid rows -> zero wir
        int fl = f < 0 ? 0 : (f > FTOT - 1 ? FTOT - 1 : f);
        const float* row = coeff + ((size_t)b * FTOT + fl) * FCL;
        frv[i]  = row[lane];
        f64v[i] = row[64];
    }
    #pragma unroll
    for (int i = 0; i < 9; ++i) {
        frv[i]  = mod_sigmoid(frv[i]);
        f64v[i] = mod_sigmoid(f64v[i]);
    }

    __syncthreads();   // pad zeros visible before scatter

    // transform: shared Chebyshev recurrence across the wave's 9 frames
    {
        float c  = __cosf(6.283185307179586f * (float)lane * (1.0f / 129.0f));
        float c2 = 2.0f * c;
        float cp = 1.0f;         // cos(0)
        float ck = c;            // cos(theta)
        float S[9];
        #pragma unroll
        for (int i = 0; i < 9; ++i) S[i] = 0.5f * rdlane(frv[i], 0);   // 0.5*fr0
        #pragma unroll 8
        for (int k = 1; k < 64; ++k) {
            #pragma unroll
            for (int i = 0; i < 9; ++i)
                S[i] = __builtin_fmaf(rdlane(frv[i], k), ck, S[i]);
            float cn = __builtin_fmaf(c2, ck, -cp);
            cp = ck; ck = cn;
        }
        #pragma unroll
        for (int i = 0; i < 9; ++i)
            S[i] = __builtin_fmaf(f64v[i], ck, S[i]);    // k = 64 term
        // window + scatter: taps 64 +- lane at float (96 +- lane)
        float w1f = 0.5f - 0.5f * __cosf(6.283185307179586f * (float)(64 + lane) * (1.0f / 129.0f));
        float w2f = 0.5f - 0.5f * __cosf(6.283185307179586f * (float)(64 - lane) * (1.0f / 129.0f));
        #pragma unroll
        for (int i = 0; i < 9; ++i) {
            int fi = wv + 4 * i;
            if (fi < NF) {
                float zp = S[i] * (2.0f / 129.0f) * vm[i];   // vm=0 -> row zeroed
                wirP[fi * PW + 96 + lane] = w1f * zp;
                wirP[fi * PW + 96 - lane] = w2f * zp;
            }
        }
    }
    __syncthreads();

    // conv + OLA: thread = (chunk 0..31, t 0..7), 8 samples each; wave = t>>1
    {
        const int chunk = tid & 31;              // output frame within block
        const int t     = tid >> 5;              // r0 = 8*t
        float a[8];
        #pragma unroll
        for (int j = 0; j < 8; ++j) a[j] = 0.0f;

        #pragma unroll
        for (int dd = 0; dd < 3; ++dd) {
            const int q  = chunk + 2 - dd;       // staged row index
            const int fq = fbase + q;
            const int fc = fq < 0 ? 0 : fq;      // fq<0 rows have wir==0 anyway
            const float4* np4 = (const float4*)(noise + ((size_t)b * FTOT + fc) * 64);
            const float4* wb  = (const float4*)wirP + q * 49 + (16 * dd + 2 * t - 8);
            // triangle bounds (wave-uniform, multiples of 4):
            //  dd0: nonzero needs s4 < 2t+2 -> S1 = 4*wv+4
            //  dd2: all-zero for s4 <= 2t-1 -> S0 = 4*wv
            int S0 = (dd == 2) ? 4 * wv : 0;
            int S1 = (dd == 0) ? 4 * wv + 4 : 16;
            conv_dd(wb, np4, S0, S1, a);
        }

        float* op = &out[(size_t)b * SAMPLES + (size_t)(fp0 + chunk) * 64 + t * 8];
        *(float4*)op       = make_float4(a[0], a[1], a[2], a[3]);
        *(float4*)(op + 4) = make_float4(a[4], a[5], a[6], a[7]);
    }
}

extern "C" void kernel_launch(void* const* d_in, const int* in_sizes, int n_in,
                              void* d_out, int out_size, void* d_ws, size_t ws_size,
                              hipStream_t stream) {
    const float* coeff = (const float*)d_in[0];
    const float* noise = (const float*)d_in[1];
    float* out = (float*)d_out;
    dim3 grid(NB * BLOCKS_PER_B);   // 64 * 128 = 8192 blocks, 256 threads each
    fn_kernel<<<grid, 256, 0, stream>>>(coeff, noise, out);
}